// Round 6
// baseline (510.294 us; speedup 1.0000x reference)
//
#include <hip/hip_runtime.h>
#include <hip/hip_bf16.h>
#include <math.h>

// ---------------------------------------------------------------------------
// ActorGNN: 4-layer GraphConv. R16b (defensive rebuild of R16 after two
// container failures — same CSR-v3 algorithm, only proven launch shapes):
//  - scan1: 512-thread blocks (512 elems each; 196 blocks) — 512-thr blocks
//    already proven by layer kernels. scan2: one 256-thread block (196
//    totals). No 1024-thr / 128-thr launches (the only novel configs R16
//    introduced vs all passing rounds).
//  - CSR build v3: E-parallel histogram -> two-level scan -> finalize ->
//    ONE E-parallel scatter into compact 6.4-MB col. 25-MB bins dropped,
//    one full random-scatter pass eliminated, no 0.77-blocks/CU phase.
//  - Layers untouched (R15 lesson: gather pinned at ~65us regardless of
//    FETCH 154->82MB => per-CU outstanding-miss-slot ceiling).
// ---------------------------------------------------------------------------

using bfrag = __attribute__((ext_vector_type(8))) short;   // 8 bf16 (4 VGPR)
using ffrag = __attribute__((ext_vector_type(4))) float;   // 4 fp32 acc

#define AGG_F_STRIDE 65             // floats; 260B row pitch (bank-spread)

__device__ __forceinline__ int load_idx32(const int* __restrict__ ei32, int is64,
                                          long long pos) {
    return is64 ? ei32[2 * pos] : ei32[pos];
}

__device__ __forceinline__ unsigned short f2b_rne(float f) {
    union { float f; unsigned u; } c;
    c.f = f;
    unsigned r = c.u + 0x7FFFu + ((c.u >> 16) & 1u);
    return (unsigned short)(r >> 16);
}

__device__ __forceinline__ float b2f(unsigned short u) {
    union { unsigned u; float f; } c;
    c.u = ((unsigned)u) << 16;
    return c.f;
}

// ---- weight prep (B^T hi/lo, 3 layers) + deg zero + int64 detect ----
__global__ __launch_bounds__(256) void bprep_init_kernel(
    const float* __restrict__ Ws1, const float* __restrict__ Wn1,
    const float* __restrict__ Ws2, const float* __restrict__ Wn2,
    const float* __restrict__ Ws3, const float* __restrict__ Wn3,
    unsigned short* __restrict__ bthi, unsigned short* __restrict__ btlo,
    const int* __restrict__ ei, int* __restrict__ deg, int* __restrict__ flag,
    int N) {
    // zero deg[] grid-stride
    for (int j = blockIdx.x * 256 + threadIdx.x; j < N; j += gridDim.x * 256)
        deg[j] = 0;
    if (blockIdx.x == 0 && threadIdx.x == 0) {
        int allz = 1;
        for (int i = 0; i < 32; ++i)
            if (ei[2 * i + 1] != 0) allz = 0;
        *flag = allz;
    }
    int i = blockIdx.x * 256 + threadIdx.x;
    if (i >= 3 * 8192) return;
    int layer = i >> 13;
    int j = i & 8191;
    int n = j >> 7, k = j & 127;
    const float* Ws = layer == 0 ? Ws1 : (layer == 1 ? Ws2 : Ws3);
    const float* Wn = layer == 0 ? Wn1 : (layer == 1 ? Wn2 : Wn3);
    float v = (k < 64) ? Ws[k * 64 + n] : Wn[(k - 64) * 64 + n];
    unsigned short hi = f2b_rne(v);
    bthi[i] = hi;
    btlo[i] = f2b_rne(v - b2f(hi));
}

// x -> bf16 hi, [n][d] layout preserved
__global__ __launch_bounds__(256) void split_x_kernel(
    const float4* __restrict__ in, ushort4* __restrict__ hi, int n4) {
    int i = blockIdx.x * blockDim.x + threadIdx.x;
    if (i >= n4) return;
    float4 v = in[i];
    ushort4 h;
    h.x = f2b_rne(v.x); h.y = f2b_rne(v.y); h.z = f2b_rne(v.z); h.w = f2b_rne(v.w);
    hi[i] = h;
}

// ---- CSR v3 stage 1: dst-degree histogram (E-parallel) ----
__global__ __launch_bounds__(256) void hist_kernel(
    const int* __restrict__ ei32, const int* __restrict__ flagp,
    int* __restrict__ deg, int E) {
    int is64 = *flagp;
    for (int e = blockIdx.x * 256 + threadIdx.x; e < E; e += gridDim.x * 256) {
        int dst = load_idx32(ei32, is64, (long long)E + e);
        atomicAdd(&deg[dst], 1);
    }
}

// ---- CSR v3 stage 2a: per-512-block exclusive scan of deg ----
__global__ __launch_bounds__(512) void scan1_kernel(
    const int* __restrict__ deg, int* __restrict__ locOff,
    int* __restrict__ btot, int N) {
    __shared__ int s[512];
    int b = blockIdx.x, t = threadIdx.x;
    int n = b * 512 + t;
    int d = (n < N) ? deg[n] : 0;
    s[t] = d;
    __syncthreads();
    for (int o = 1; o < 512; o <<= 1) {
        int v = (t >= o) ? s[t - o] : 0;
        __syncthreads();
        s[t] += v;
        __syncthreads();
    }
    if (n < N) locOff[n] = s[t] - d;   // exclusive
    if (t == 511) btot[b] = s[t];
}

// ---- CSR v3 stage 2b: scan block totals (one 256-thr block; nb<=256) ----
__global__ __launch_bounds__(256) void scan2_kernel(
    const int* __restrict__ btot, int* __restrict__ bbase, int nb) {
    __shared__ int s[256];
    int t = threadIdx.x;
    int d = (t < nb) ? btot[t] : 0;
    s[t] = d;
    __syncthreads();
    for (int o = 1; o < 256; o <<= 1) {
        int v = (t >= o) ? s[t - o] : 0;
        __syncthreads();
        s[t] += v;
        __syncthreads();
    }
    if (t < nb) bbase[t] = s[t] - d;   // exclusive
}

// ---- CSR v3 stage 2c: absolute offsets + cursor + dinv (N-parallel) ----
__global__ __launch_bounds__(256) void finalize_kernel(
    const int* __restrict__ deg, const int* __restrict__ locOff,
    const int* __restrict__ bbase, int2* __restrict__ offp,
    int* __restrict__ cur, float* __restrict__ dinv, int N) {
    int n = blockIdx.x * 256 + threadIdx.x;
    if (n >= N) return;
    int d = deg[n];
    int start = locOff[n] + bbase[n >> 9];
    offp[n] = make_int2(start, start + d);
    cur[n] = start;
    dinv[n] = 1.0f / fmaxf((float)d, 1.0f);
}

// ---- CSR v3 stage 3: single scatter pass (E-parallel) ----
__global__ __launch_bounds__(256) void scatter_kernel(
    const int* __restrict__ ei32, const int* __restrict__ flagp,
    int* __restrict__ cur, int* __restrict__ col, int E) {
    int is64 = *flagp;
    for (int e = blockIdx.x * 256 + threadIdx.x; e < E; e += gridDim.x * 256) {
        int src = load_idx32(ei32, is64, e);
        int dst = load_idx32(ei32, is64, (long long)E + e);
        int p = atomicAdd(&cur[dst], 1);
        col[p] = src;
    }
}

// ---- gather helpers ----
__device__ __forceinline__ void acc4(float4& a, ushort4 u) {
    a.x += b2f(u.x); a.y += b2f(u.y); a.z += b2f(u.z); a.w += b2f(u.w);
}

__device__ __forceinline__ void fma4(float4& a, float m, ushort4 u) {
    a.x = fmaf(m, b2f(u.x), a.x);
    a.y = fmaf(m, b2f(u.y), a.y);
    a.z = fmaf(m, b2f(u.z), a.z);
    a.w = fmaf(m, b2f(u.w), a.w);
}

// ---- gather v5: one 16-lane group accumulates HALF a node's edge range
// into f32 LDS partials. Lane t16 owns dims t16*4..+3. 8-deep main loop
// (one latency round at deg/2 ~= 8) + predicated tail. ----
__device__ __forceinline__ void gather_half(
    const unsigned short* __restrict__ Hhi, const int* __restrict__ col,
    float* __restrict__ dstF, int e, int end, int t16) {
    float4 a0 = make_float4(0.f, 0.f, 0.f, 0.f);
    float4 a1 = a0, a2 = a0, a3 = a0;
    const unsigned short* __restrict__ Hq = Hhi + t16 * 4;
    for (; e + 8 <= end; e += 8) {
        int s0 = col[e + 0], s1 = col[e + 1], s2 = col[e + 2], s3 = col[e + 3];
        int s4 = col[e + 4], s5 = col[e + 5], s6 = col[e + 6], s7 = col[e + 7];
        ushort4 u0 = *(const ushort4*)&Hq[(size_t)s0 * 64];
        ushort4 u1 = *(const ushort4*)&Hq[(size_t)s1 * 64];
        ushort4 u2 = *(const ushort4*)&Hq[(size_t)s2 * 64];
        ushort4 u3 = *(const ushort4*)&Hq[(size_t)s3 * 64];
        ushort4 u4 = *(const ushort4*)&Hq[(size_t)s4 * 64];
        ushort4 u5 = *(const ushort4*)&Hq[(size_t)s5 * 64];
        ushort4 u6 = *(const ushort4*)&Hq[(size_t)s6 * 64];
        ushort4 u7 = *(const ushort4*)&Hq[(size_t)s7 * 64];
        acc4(a0, u0); acc4(a1, u1); acc4(a2, u2); acc4(a3, u3);
        acc4(a0, u4); acc4(a1, u5); acc4(a2, u6); acc4(a3, u7);
    }
    int rem = end - e;                 // 0..7
    if (rem > 0) {
        int last = end - 1;
#pragma unroll
        for (int j = 0; j < 7; ++j) {
            int idx = e + j;
            int cl = idx < last ? idx : last;
            int s = col[cl];
            ushort4 u = *(const ushort4*)&Hq[(size_t)s * 64];
            float m = (j < rem) ? 1.0f : 0.0f;
            if ((j & 3) == 0) fma4(a0, m, u);
            else if ((j & 3) == 1) fma4(a1, m, u);
            else if ((j & 3) == 2) fma4(a2, m, u);
            else fma4(a3, m, u);
        }
    }
    float4 s;
    s.x = (a0.x + a1.x) + (a2.x + a3.x);
    s.y = (a0.y + a1.y) + (a2.y + a3.y);
    s.z = (a0.z + a1.z) + (a2.z + a3.z);
    s.w = (a0.w + a1.w) + (a2.w + a3.w);
    *(float4*)&dstF[t16 * 4] = s;
}

// combine two f32 half-rows, scale by dinv, convert to bf16 frag
__device__ __forceinline__ bfrag cvt8(const float* __restrict__ p0,
                                      const float* __restrict__ p1, float di) {
    bfrag r;
#pragma unroll
    for (int i = 0; i < 8; ++i)
        r[i] = (short)f2b_rne((p0[i] + p1[i]) * di);
    return r;
}

// ---- fused layer v5: block = 8 waves / 32 groups / 16 nodes. Group grp
// gathers half (grp&1) of node grp>>1. Dense phase: waves 0-3, wave w owns
// out-cols w*16..+15 for all 16 nodes. ----
__global__ __launch_bounds__(512, 8) void layer_fused_kernel(
    const unsigned short* __restrict__ Hhi, const int2* __restrict__ offp,
    const int* __restrict__ col, const float* __restrict__ dinv,
    const unsigned short* __restrict__ Bthi, const unsigned short* __restrict__ Btlo,
    const float* __restrict__ b, unsigned short* __restrict__ Dhi, int N) {
    __shared__ float aggF[32 * AGG_F_STRIDE];
    int wave = threadIdx.x >> 6;
    int lane = threadIdx.x & 63;
    int g = lane >> 4;
    int t16 = lane & 15;
    int n0 = blockIdx.x * 16;
    int grp = wave * 4 + g;          // 0..31
    int li = grp >> 1, half = grp & 1;
    int n = n0 + li;
    int e0 = 0, e1 = 0;
    if (n < N) {
        int2 oo = offp[n];
        int d = oo.y - oo.x;
        int c0 = (d + 1) >> 1;
        e0 = half ? oo.x + c0 : oo.x;
        e1 = half ? oo.y : oo.x + c0;
    }
    gather_half(Hhi, col, &aggF[grp * AGG_F_STRIDE], e0, e1, t16);
    __syncthreads();
    if (wave < 4) {
        int m = t16, quad = g;
        int nr = n0 + m;
        if (nr > N - 1) nr = N - 1;
        float di = dinv[nr];
        const float* r0 = &aggF[(m * 2 + 0) * AGG_F_STRIDE];
        const float* r1 = &aggF[(m * 2 + 1) * AGG_F_STRIDE];
        const unsigned short* hrow = Hhi + (size_t)nr * 64 + quad * 8;
        bfrag ah[4];
        ah[0] = *(const bfrag*)(hrow);
        ah[1] = *(const bfrag*)(hrow + 32);
        ah[2] = cvt8(r0 + quad * 8, r1 + quad * 8, di);
        ah[3] = cvt8(r0 + 32 + quad * 8, r1 + 32 + quad * 8, di);
        int oc = wave * 16 + m;  // out col
        float bl = b[oc];
        ffrag acc = {bl, bl, bl, bl};
#pragma unroll
        for (int c = 0; c < 4; ++c) {
            bfrag bh = *(const bfrag*)(Bthi + (size_t)oc * 128 + c * 32 + quad * 8);
            bfrag bw = *(const bfrag*)(Btlo + (size_t)oc * 128 + c * 32 + quad * 8);
            acc = __builtin_amdgcn_mfma_f32_16x16x32_bf16(ah[c], bh, acc, 0, 0, 0);
            acc = __builtin_amdgcn_mfma_f32_16x16x32_bf16(ah[c], bw, acc, 0, 0, 0);
        }
#pragma unroll
        for (int r = 0; r < 4; ++r) {
            int node = n0 + quad * 4 + r;
            if (node < N)
                Dhi[(size_t)node * 64 + oc] = f2b_rne(fmaxf(acc[r], 0.f));
        }
    }
}

// ---- fused layer 3 + layer-4 pre-transform ----
__global__ __launch_bounds__(512, 8) void layer_fused_last_kernel(
    const unsigned short* __restrict__ Hhi, const int2* __restrict__ offp,
    const int* __restrict__ col, const float* __restrict__ dinv,
    const unsigned short* __restrict__ Bthi, const unsigned short* __restrict__ Btlo,
    const float* __restrict__ b, const float* __restrict__ Ws4,
    const float* __restrict__ Wn4, float* __restrict__ sbuf,
    float* __restrict__ gbuf, int N) {
    __shared__ float aggF[32 * AGG_F_STRIDE];
    __shared__ float sPart[4][16];
    __shared__ float gPart[4][16];
    int wave = threadIdx.x >> 6;
    int lane = threadIdx.x & 63;
    int g = lane >> 4;
    int t16 = lane & 15;
    int n0 = blockIdx.x * 16;
    int grp = wave * 4 + g;
    int li = grp >> 1, half = grp & 1;
    int n = n0 + li;
    int e0 = 0, e1 = 0;
    if (n < N) {
        int2 oo = offp[n];
        int d = oo.y - oo.x;
        int c0 = (d + 1) >> 1;
        e0 = half ? oo.x + c0 : oo.x;
        e1 = half ? oo.y : oo.x + c0;
    }
    gather_half(Hhi, col, &aggF[grp * AGG_F_STRIDE], e0, e1, t16);
    __syncthreads();
    if (wave < 4) {
        int m = t16, quad = g;
        int nr = n0 + m;
        if (nr > N - 1) nr = N - 1;
        float di = dinv[nr];
        const float* r0 = &aggF[(m * 2 + 0) * AGG_F_STRIDE];
        const float* r1 = &aggF[(m * 2 + 1) * AGG_F_STRIDE];
        const unsigned short* hrow = Hhi + (size_t)nr * 64 + quad * 8;
        bfrag ah[4];
        ah[0] = *(const bfrag*)(hrow);
        ah[1] = *(const bfrag*)(hrow + 32);
        ah[2] = cvt8(r0 + quad * 8, r1 + quad * 8, di);
        ah[3] = cvt8(r0 + 32 + quad * 8, r1 + 32 + quad * 8, di);
        int oc = wave * 16 + m;
        float bl = b[oc];
        ffrag acc = {bl, bl, bl, bl};
#pragma unroll
        for (int c = 0; c < 4; ++c) {
            bfrag bh = *(const bfrag*)(Bthi + (size_t)oc * 128 + c * 32 + quad * 8);
            bfrag bw = *(const bfrag*)(Btlo + (size_t)oc * 128 + c * 32 + quad * 8);
            acc = __builtin_amdgcn_mfma_f32_16x16x32_bf16(ah[c], bh, acc, 0, 0, 0);
            acc = __builtin_amdgcn_mfma_f32_16x16x32_bf16(ah[c], bw, acc, 0, 0, 0);
        }
        float w4s = Ws4[oc], w4n = Wn4[oc];
#pragma unroll
        for (int r = 0; r < 4; ++r) {
            float v = fmaxf(acc[r], 0.f);
            float ps = v * w4s;
            float pg = v * w4n;
#pragma unroll
            for (int mask = 1; mask <= 8; mask <<= 1) {
                ps += __shfl_xor(ps, mask, 64);
                pg += __shfl_xor(pg, mask, 64);
            }
            if (m == 0) {
                sPart[wave][quad * 4 + r] = ps;
                gPart[wave][quad * 4 + r] = pg;
            }
        }
    }
    __syncthreads();
    if (threadIdx.x < 16) {
        int node = n0 + threadIdx.x;
        if (node < N) {
            float s = sPart[0][threadIdx.x] + sPart[1][threadIdx.x] +
                      sPart[2][threadIdx.x] + sPart[3][threadIdx.x];
            float gg = gPart[0][threadIdx.x] + gPart[1][threadIdx.x] +
                       gPart[2][threadIdx.x] + gPart[3][threadIdx.x];
            sbuf[node] = s;
            gbuf[node] = gg;
        }
    }
}

// thread per node: scalar CSR gather of g (400 KB, L2-resident) + sigmoid
__global__ __launch_bounds__(256) void final_kernel(
    const float* __restrict__ s, const float* __restrict__ dinv,
    const float* __restrict__ g, const int2* __restrict__ offp,
    const int* __restrict__ col,
    const float* __restrict__ b4, float* __restrict__ out, int N) {
    int n = blockIdx.x * blockDim.x + threadIdx.x;
    if (n >= N) return;
    float a = 0.f;
    int2 oo = offp[n];
    for (int e = oo.x; e < oo.y; ++e) a += g[col[e]];
    float z = s[n] + dinv[n] * a + b4[0];
    out[n] = 1.0f / (1.0f + expf(-z));
}

static inline int cdiv(long long a, long long b) { return (int)((a + b - 1) / b); }

extern "C" void kernel_launch(void* const* d_in, const int* in_sizes, int n_in,
                              void* d_out, int out_size, void* d_ws, size_t ws_size,
                              hipStream_t stream) {
    const float* x   = (const float*)d_in[0];
    const int*   ei  = (const int*)d_in[1];
    const float* Ws1 = (const float*)d_in[2];
    const float* Wn1 = (const float*)d_in[3];
    const float* b1  = (const float*)d_in[4];
    const float* Ws2 = (const float*)d_in[5];
    const float* Wn2 = (const float*)d_in[6];
    const float* b2  = (const float*)d_in[7];
    const float* Ws3 = (const float*)d_in[8];
    const float* Wn3 = (const float*)d_in[9];
    const float* b3  = (const float*)d_in[10];
    const float* Ws4 = (const float*)d_in[11];
    const float* Wn4 = (const float*)d_in[12];
    const float* b4  = (const float*)d_in[13];
    float* out = (float*)d_out;

    const int N = in_sizes[0] / 64;
    const int E = in_sizes[1] / 2;
    const int nb512 = cdiv(N, 512);                      // scan blocks (<=256)

    // workspace layout (8-B aligned head first)
    int2* offp = (int2*)d_ws;                            // N
    int* col   = (int*)(offp + N);                       // E
    unsigned short* HhiA = (unsigned short*)(col + E);   // N*64
    unsigned short* HhiB = HhiA + (size_t)N * 64;        // N*64
    unsigned short* Bth  = HhiB + (size_t)N * 64;        // 3*8192
    unsigned short* Btl  = Bth + 3 * 8192;               // 3*8192
    float* dinv = (float*)(Btl + 3 * 8192);              // N
    float* sbuf = dinv + N;                              // N
    float* gbuf = sbuf + N;                              // N
    int*   deg    = (int*)(gbuf + N);                    // N
    int*   locOff = deg + N;                             // N
    int*   cur    = locOff + N;                          // N
    int*   btot   = cur + N;                             // 256
    int*   bbase  = btot + 256;                          // 256
    int*   flag   = bbase + 256;                         // 1

    const int BT = 256;
    const int gridN  = cdiv(N, BT);
    const int gridL  = cdiv(N, 16);                      // 16 nodes/block
    const int gridE  = min(2048, cdiv(E, BT));

    // ---- prep: weights + deg-zero + flag, x->bf16 ----
    bprep_init_kernel<<<128, BT, 0, stream>>>(Ws1, Wn1, Ws2, Wn2, Ws3, Wn3,
                                              Bth, Btl, ei, deg, flag, N);
    split_x_kernel<<<cdiv((long long)N * 16, BT), BT, 0, stream>>>(
        (const float4*)x, (ushort4*)HhiA, N * 16);

    // ---- CSR build v3: hist -> scan -> finalize -> scatter ----
    hist_kernel<<<gridE, BT, 0, stream>>>(ei, flag, deg, E);
    scan1_kernel<<<nb512, 512, 0, stream>>>(deg, locOff, btot, N);
    scan2_kernel<<<1, BT, 0, stream>>>(btot, bbase, nb512);
    finalize_kernel<<<gridN, BT, 0, stream>>>(deg, locOff, bbase, offp, cur, dinv, N);
    scatter_kernel<<<gridE, BT, 0, stream>>>(ei, flag, cur, col, E);

    // ---- layers 1-3 (fused gather+dense v5, 512-thread blocks) ----
    layer_fused_kernel<<<gridL, 512, 0, stream>>>(HhiA, offp, col, dinv,
                                                  Bth, Btl, b1, HhiB, N);
    layer_fused_kernel<<<gridL, 512, 0, stream>>>(HhiB, offp, col, dinv,
                                                  Bth + 8192, Btl + 8192, b2, HhiA, N);
    layer_fused_last_kernel<<<gridL, 512, 0, stream>>>(HhiA, offp, col, dinv,
                                                       Bth + 16384, Btl + 16384, b3,
                                                       Ws4, Wn4, sbuf, gbuf, N);

    // ---- layer 4 (64->1): scalar CSR gather + sigmoid ----
    final_kernel<<<gridN, BT, 0, stream>>>(sbuf, dinv, gbuf, offp, col, b4, out, N);
}

// Round 7
// 338.114 us; speedup vs baseline: 1.5092x; 1.5092x over previous
//
#include <hip/hip_runtime.h>
#include <hip/hip_bf16.h>
#include <math.h>

// ---------------------------------------------------------------------------
// ActorGNN: 4-layer GraphConv. R17 (= R15 CSR revert):
//  - R16/R16b lesson (measured): direct global scatter = 147us, WRITE_SIZE
//    106MB (1.6M isolated 4-B stores x 64-B line RMW). The binA+bucketCSR
//    two-pass build is a radix sort: binA writes ~12-entry runs per
//    (block,bucket) that L2-merges; bucketCSR scatters within a ~28-KB
//    L2-resident region. Reverted to that (R15 form, 343us total).
//  - Layers: gather v5 (512thr/8waves/32 half-groups/16 nodes), f32 LDS
//    partials, hi-only bf16 H, split-weight MFMA dense. Pinned at ~65us by
//    per-CU random-request rate (~25cyc/req) — structural for this approach.
//  - final_kernel: 4-wide independent-accumulator unroll (minor).
// ---------------------------------------------------------------------------

using bfrag = __attribute__((ext_vector_type(8))) short;   // 8 bf16 (4 VGPR)
using ffrag = __attribute__((ext_vector_type(4))) float;   // 4 fp32 acc

#define BKT_SHIFT 9                 // 512 nodes per bucket
#define BKT_NODES (1 << BKT_SHIFT)
#define AGG_F_STRIDE 65             // floats; 260B row pitch (bank-spread)

__device__ __forceinline__ int load_idx32(const int* __restrict__ ei32, int is64,
                                          long long pos) {
    return is64 ? ei32[2 * pos] : ei32[pos];
}

__device__ __forceinline__ unsigned short f2b_rne(float f) {
    union { float f; unsigned u; } c;
    c.f = f;
    unsigned r = c.u + 0x7FFFu + ((c.u >> 16) & 1u);
    return (unsigned short)(r >> 16);
}

__device__ __forceinline__ float b2f(unsigned short u) {
    union { unsigned u; float f; } c;
    c.u = ((unsigned)u) << 16;
    return c.f;
}

// ---- weight prep (B^T hi/lo, 3 layers) + bktc zero + int64 detect ----
__global__ __launch_bounds__(256) void bprep_init_kernel(
    const float* __restrict__ Ws1, const float* __restrict__ Wn1,
    const float* __restrict__ Ws2, const float* __restrict__ Wn2,
    const float* __restrict__ Ws3, const float* __restrict__ Wn3,
    unsigned short* __restrict__ bthi, unsigned short* __restrict__ btlo,
    const int* __restrict__ ei, int* __restrict__ bktc, int* __restrict__ flag) {
    if (blockIdx.x == 0) {
        bktc[threadIdx.x] = 0;
        if (threadIdx.x == 0) {
            int allz = 1;
            for (int i = 0; i < 32; ++i)
                if (ei[2 * i + 1] != 0) allz = 0;
            *flag = allz;
        }
    }
    int i = blockIdx.x * 256 + threadIdx.x;
    if (i >= 3 * 8192) return;
    int layer = i >> 13;
    int j = i & 8191;
    int n = j >> 7, k = j & 127;
    const float* Ws = layer == 0 ? Ws1 : (layer == 1 ? Ws2 : Ws3);
    const float* Wn = layer == 0 ? Wn1 : (layer == 1 ? Wn2 : Wn3);
    float v = (k < 64) ? Ws[k * 64 + n] : Wn[(k - 64) * 64 + n];
    unsigned short hi = f2b_rne(v);
    bthi[i] = hi;
    btlo[i] = f2b_rne(v - b2f(hi));
}

// x -> bf16 hi, [n][d] layout preserved
__global__ __launch_bounds__(256) void split_x_kernel(
    const float4* __restrict__ in, ushort4* __restrict__ hi, int n4) {
    int i = blockIdx.x * blockDim.x + threadIdx.x;
    if (i >= n4) return;
    float4 v = in[i];
    ushort4 h;
    h.x = f2b_rne(v.x); h.y = f2b_rne(v.y); h.z = f2b_rne(v.z); h.w = f2b_rne(v.w);
    hi[i] = h;
}

// ---- PassA: bin edges into dst-buckets, packed (dstLocal<<23 | src) ----
__global__ __launch_bounds__(256) void binA_kernel(
    const int* __restrict__ ei32, const int* __restrict__ flagp,
    int* __restrict__ bktCnt, unsigned* __restrict__ bins, int E, int nbkt,
    int cap, int chunksz) {
    __shared__ int cnt[256];
    __shared__ int base[256];
    int is64 = *flagp;
    int elo = blockIdx.x * chunksz;
    int ehi = min(E, elo + chunksz);
    if (elo >= E) return;
    for (int i = threadIdx.x; i < nbkt; i += 256) cnt[i] = 0;
    __syncthreads();
    for (int e = elo + (int)threadIdx.x; e < ehi; e += 256) {
        int dst = load_idx32(ei32, is64, (long long)E + e);
        atomicAdd(&cnt[dst >> BKT_SHIFT], 1);
    }
    __syncthreads();
    for (int i = threadIdx.x; i < nbkt; i += 256) {
        base[i] = atomicAdd(&bktCnt[i], cnt[i]);
        cnt[i] = 0;
    }
    __syncthreads();
    for (int e = elo + (int)threadIdx.x; e < ehi; e += 256) {
        int dst = load_idx32(ei32, is64, (long long)E + e);
        int src = load_idx32(ei32, is64, e);
        int b = dst >> BKT_SHIFT;
        int r = atomicAdd(&cnt[b], 1);
        bins[(size_t)b * cap + base[b] + r] =
            ((unsigned)(dst & (BKT_NODES - 1)) << 23) | (unsigned)src;
    }
}

// ---- bucketCSR: degree + local scan + scatter + dinv, one kernel ----
__global__ __launch_bounds__(256) void bucketCSR_kernel(
    const int* __restrict__ bktCnt, const unsigned* __restrict__ bins,
    int2* __restrict__ offp, int* __restrict__ col,
    float* __restrict__ dinv, int N, int cap) {
    __shared__ int deg[BKT_NODES];
    __shared__ int loc[BKT_NODES];
    __shared__ int ssum[256];
    int b = blockIdx.x;
    int lo = b << BKT_SHIFT;
    int n = min(BKT_NODES, N - lo);
    for (int i = threadIdx.x; i < BKT_NODES; i += 256) deg[i] = 0;
    __syncthreads();
    int cnt = bktCnt[b];
    const unsigned* bb = bins + (size_t)b * cap;
    for (int i = threadIdx.x; i < cnt; i += 256)
        atomicAdd(&deg[bb[i] >> 23], 1);
    __syncthreads();
    int t = threadIdx.x;
    int d0 = deg[2 * t], d1 = deg[2 * t + 1];
    int s = d0 + d1;
    ssum[t] = s;
    __syncthreads();
    for (int o = 1; o < 256; o <<= 1) {
        int v = (t >= o) ? ssum[t - o] : 0;
        __syncthreads();
        ssum[t] += v;
        __syncthreads();
    }
    int excl = ssum[t] - s;
    loc[2 * t] = excl;
    loc[2 * t + 1] = excl + d0;
    __syncthreads();
    int base = b * cap;
    for (int i = threadIdx.x; i < n; i += 256) {
        int d = deg[i];
        offp[lo + i] = make_int2(base + loc[i], base + loc[i] + d);
        dinv[lo + i] = 1.0f / fmaxf((float)d, 1.0f);
    }
    __syncthreads();
    for (int i = threadIdx.x; i < cnt; i += 256) {
        unsigned p = bb[i];
        int pos = atomicAdd(&loc[p >> 23], 1);
        col[base + pos] = (int)(p & 0x7FFFFFu);
    }
}

// ---- gather helpers ----
__device__ __forceinline__ void acc4(float4& a, ushort4 u) {
    a.x += b2f(u.x); a.y += b2f(u.y); a.z += b2f(u.z); a.w += b2f(u.w);
}

__device__ __forceinline__ void fma4(float4& a, float m, ushort4 u) {
    a.x = fmaf(m, b2f(u.x), a.x);
    a.y = fmaf(m, b2f(u.y), a.y);
    a.z = fmaf(m, b2f(u.z), a.z);
    a.w = fmaf(m, b2f(u.w), a.w);
}

// ---- gather v5: one 16-lane group accumulates HALF a node's edge range
// into f32 LDS partials. Lane t16 owns dims t16*4..+3. 8-deep main loop
// (one latency round at deg/2 ~= 8) + predicated tail. ----
__device__ __forceinline__ void gather_half(
    const unsigned short* __restrict__ Hhi, const int* __restrict__ col,
    float* __restrict__ dstF, int e, int end, int t16) {
    float4 a0 = make_float4(0.f, 0.f, 0.f, 0.f);
    float4 a1 = a0, a2 = a0, a3 = a0;
    const unsigned short* __restrict__ Hq = Hhi + t16 * 4;
    for (; e + 8 <= end; e += 8) {
        int s0 = col[e + 0], s1 = col[e + 1], s2 = col[e + 2], s3 = col[e + 3];
        int s4 = col[e + 4], s5 = col[e + 5], s6 = col[e + 6], s7 = col[e + 7];
        ushort4 u0 = *(const ushort4*)&Hq[(size_t)s0 * 64];
        ushort4 u1 = *(const ushort4*)&Hq[(size_t)s1 * 64];
        ushort4 u2 = *(const ushort4*)&Hq[(size_t)s2 * 64];
        ushort4 u3 = *(const ushort4*)&Hq[(size_t)s3 * 64];
        ushort4 u4 = *(const ushort4*)&Hq[(size_t)s4 * 64];
        ushort4 u5 = *(const ushort4*)&Hq[(size_t)s5 * 64];
        ushort4 u6 = *(const ushort4*)&Hq[(size_t)s6 * 64];
        ushort4 u7 = *(const ushort4*)&Hq[(size_t)s7 * 64];
        acc4(a0, u0); acc4(a1, u1); acc4(a2, u2); acc4(a3, u3);
        acc4(a0, u4); acc4(a1, u5); acc4(a2, u6); acc4(a3, u7);
    }
    int rem = end - e;                 // 0..7
    if (rem > 0) {
        int last = end - 1;
#pragma unroll
        for (int j = 0; j < 7; ++j) {
            int idx = e + j;
            int cl = idx < last ? idx : last;
            int s = col[cl];
            ushort4 u = *(const ushort4*)&Hq[(size_t)s * 64];
            float m = (j < rem) ? 1.0f : 0.0f;
            if ((j & 3) == 0) fma4(a0, m, u);
            else if ((j & 3) == 1) fma4(a1, m, u);
            else if ((j & 3) == 2) fma4(a2, m, u);
            else fma4(a3, m, u);
        }
    }
    float4 s;
    s.x = (a0.x + a1.x) + (a2.x + a3.x);
    s.y = (a0.y + a1.y) + (a2.y + a3.y);
    s.z = (a0.z + a1.z) + (a2.z + a3.z);
    s.w = (a0.w + a1.w) + (a2.w + a3.w);
    *(float4*)&dstF[t16 * 4] = s;
}

// combine two f32 half-rows, scale by dinv, convert to bf16 frag
__device__ __forceinline__ bfrag cvt8(const float* __restrict__ p0,
                                      const float* __restrict__ p1, float di) {
    bfrag r;
#pragma unroll
    for (int i = 0; i < 8; ++i)
        r[i] = (short)f2b_rne((p0[i] + p1[i]) * di);
    return r;
}

// ---- fused layer v5: block = 8 waves / 32 groups / 16 nodes. Group grp
// gathers half (grp&1) of node grp>>1. Dense phase: waves 0-3, wave w owns
// out-cols w*16..+15 for all 16 nodes. ----
__global__ __launch_bounds__(512, 8) void layer_fused_kernel(
    const unsigned short* __restrict__ Hhi, const int2* __restrict__ offp,
    const int* __restrict__ col, const float* __restrict__ dinv,
    const unsigned short* __restrict__ Bthi, const unsigned short* __restrict__ Btlo,
    const float* __restrict__ b, unsigned short* __restrict__ Dhi, int N) {
    __shared__ float aggF[32 * AGG_F_STRIDE];
    int wave = threadIdx.x >> 6;
    int lane = threadIdx.x & 63;
    int g = lane >> 4;
    int t16 = lane & 15;
    int n0 = blockIdx.x * 16;
    int grp = wave * 4 + g;          // 0..31
    int li = grp >> 1, half = grp & 1;
    int n = n0 + li;
    int e0 = 0, e1 = 0;
    if (n < N) {
        int2 oo = offp[n];
        int d = oo.y - oo.x;
        int c0 = (d + 1) >> 1;
        e0 = half ? oo.x + c0 : oo.x;
        e1 = half ? oo.y : oo.x + c0;
    }
    gather_half(Hhi, col, &aggF[grp * AGG_F_STRIDE], e0, e1, t16);
    __syncthreads();
    if (wave < 4) {
        int m = t16, quad = g;
        int nr = n0 + m;
        if (nr > N - 1) nr = N - 1;
        float di = dinv[nr];
        const float* r0 = &aggF[(m * 2 + 0) * AGG_F_STRIDE];
        const float* r1 = &aggF[(m * 2 + 1) * AGG_F_STRIDE];
        const unsigned short* hrow = Hhi + (size_t)nr * 64 + quad * 8;
        bfrag ah[4];
        ah[0] = *(const bfrag*)(hrow);
        ah[1] = *(const bfrag*)(hrow + 32);
        ah[2] = cvt8(r0 + quad * 8, r1 + quad * 8, di);
        ah[3] = cvt8(r0 + 32 + quad * 8, r1 + 32 + quad * 8, di);
        int oc = wave * 16 + m;  // out col
        float bl = b[oc];
        ffrag acc = {bl, bl, bl, bl};
#pragma unroll
        for (int c = 0; c < 4; ++c) {
            bfrag bh = *(const bfrag*)(Bthi + (size_t)oc * 128 + c * 32 + quad * 8);
            bfrag bw = *(const bfrag*)(Btlo + (size_t)oc * 128 + c * 32 + quad * 8);
            acc = __builtin_amdgcn_mfma_f32_16x16x32_bf16(ah[c], bh, acc, 0, 0, 0);
            acc = __builtin_amdgcn_mfma_f32_16x16x32_bf16(ah[c], bw, acc, 0, 0, 0);
        }
#pragma unroll
        for (int r = 0; r < 4; ++r) {
            int node = n0 + quad * 4 + r;
            if (node < N)
                Dhi[(size_t)node * 64 + oc] = f2b_rne(fmaxf(acc[r], 0.f));
        }
    }
}

// ---- fused layer 3 + layer-4 pre-transform ----
__global__ __launch_bounds__(512, 8) void layer_fused_last_kernel(
    const unsigned short* __restrict__ Hhi, const int2* __restrict__ offp,
    const int* __restrict__ col, const float* __restrict__ dinv,
    const unsigned short* __restrict__ Bthi, const unsigned short* __restrict__ Btlo,
    const float* __restrict__ b, const float* __restrict__ Ws4,
    const float* __restrict__ Wn4, float* __restrict__ sbuf,
    float* __restrict__ gbuf, int N) {
    __shared__ float aggF[32 * AGG_F_STRIDE];
    __shared__ float sPart[4][16];
    __shared__ float gPart[4][16];
    int wave = threadIdx.x >> 6;
    int lane = threadIdx.x & 63;
    int g = lane >> 4;
    int t16 = lane & 15;
    int n0 = blockIdx.x * 16;
    int grp = wave * 4 + g;
    int li = grp >> 1, half = grp & 1;
    int n = n0 + li;
    int e0 = 0, e1 = 0;
    if (n < N) {
        int2 oo = offp[n];
        int d = oo.y - oo.x;
        int c0 = (d + 1) >> 1;
        e0 = half ? oo.x + c0 : oo.x;
        e1 = half ? oo.y : oo.x + c0;
    }
    gather_half(Hhi, col, &aggF[grp * AGG_F_STRIDE], e0, e1, t16);
    __syncthreads();
    if (wave < 4) {
        int m = t16, quad = g;
        int nr = n0 + m;
        if (nr > N - 1) nr = N - 1;
        float di = dinv[nr];
        const float* r0 = &aggF[(m * 2 + 0) * AGG_F_STRIDE];
        const float* r1 = &aggF[(m * 2 + 1) * AGG_F_STRIDE];
        const unsigned short* hrow = Hhi + (size_t)nr * 64 + quad * 8;
        bfrag ah[4];
        ah[0] = *(const bfrag*)(hrow);
        ah[1] = *(const bfrag*)(hrow + 32);
        ah[2] = cvt8(r0 + quad * 8, r1 + quad * 8, di);
        ah[3] = cvt8(r0 + 32 + quad * 8, r1 + 32 + quad * 8, di);
        int oc = wave * 16 + m;
        float bl = b[oc];
        ffrag acc = {bl, bl, bl, bl};
#pragma unroll
        for (int c = 0; c < 4; ++c) {
            bfrag bh = *(const bfrag*)(Bthi + (size_t)oc * 128 + c * 32 + quad * 8);
            bfrag bw = *(const bfrag*)(Btlo + (size_t)oc * 128 + c * 32 + quad * 8);
            acc = __builtin_amdgcn_mfma_f32_16x16x32_bf16(ah[c], bh, acc, 0, 0, 0);
            acc = __builtin_amdgcn_mfma_f32_16x16x32_bf16(ah[c], bw, acc, 0, 0, 0);
        }
        float w4s = Ws4[oc], w4n = Wn4[oc];
#pragma unroll
        for (int r = 0; r < 4; ++r) {
            float v = fmaxf(acc[r], 0.f);
            float ps = v * w4s;
            float pg = v * w4n;
#pragma unroll
            for (int mask = 1; mask <= 8; mask <<= 1) {
                ps += __shfl_xor(ps, mask, 64);
                pg += __shfl_xor(pg, mask, 64);
            }
            if (m == 0) {
                sPart[wave][quad * 4 + r] = ps;
                gPart[wave][quad * 4 + r] = pg;
            }
        }
    }
    __syncthreads();
    if (threadIdx.x < 16) {
        int node = n0 + threadIdx.x;
        if (node < N) {
            float s = sPart[0][threadIdx.x] + sPart[1][threadIdx.x] +
                      sPart[2][threadIdx.x] + sPart[3][threadIdx.x];
            float gg = gPart[0][threadIdx.x] + gPart[1][threadIdx.x] +
                       gPart[2][threadIdx.x] + gPart[3][threadIdx.x];
            sbuf[node] = s;
            gbuf[node] = gg;
        }
    }
}

// thread per node: scalar CSR gather of g (400 KB, L2-resident) + sigmoid
__global__ __launch_bounds__(256) void final_kernel(
    const float* __restrict__ s, const float* __restrict__ dinv,
    const float* __restrict__ g, const int2* __restrict__ offp,
    const int* __restrict__ col,
    const float* __restrict__ b4, float* __restrict__ out, int N) {
    int n = blockIdx.x * blockDim.x + threadIdx.x;
    if (n >= N) return;
    float a0 = 0.f, a1 = 0.f, a2 = 0.f, a3 = 0.f;
    int2 oo = offp[n];
    int e = oo.x;
    for (; e + 4 <= oo.y; e += 4) {
        int c0 = col[e], c1 = col[e + 1], c2 = col[e + 2], c3 = col[e + 3];
        a0 += g[c0]; a1 += g[c1]; a2 += g[c2]; a3 += g[c3];
    }
    for (; e < oo.y; ++e) a0 += g[col[e]];
    float z = s[n] + dinv[n] * ((a0 + a1) + (a2 + a3)) + b4[0];
    out[n] = 1.0f / (1.0f + expf(-z));
}

static inline int cdiv(long long a, long long b) { return (int)((a + b - 1) / b); }

extern "C" void kernel_launch(void* const* d_in, const int* in_sizes, int n_in,
                              void* d_out, int out_size, void* d_ws, size_t ws_size,
                              hipStream_t stream) {
    const float* x   = (const float*)d_in[0];
    const int*   ei  = (const int*)d_in[1];
    const float* Ws1 = (const float*)d_in[2];
    const float* Wn1 = (const float*)d_in[3];
    const float* b1  = (const float*)d_in[4];
    const float* Ws2 = (const float*)d_in[5];
    const float* Wn2 = (const float*)d_in[6];
    const float* b2  = (const float*)d_in[7];
    const float* Ws3 = (const float*)d_in[8];
    const float* Wn3 = (const float*)d_in[9];
    const float* b3  = (const float*)d_in[10];
    const float* Ws4 = (const float*)d_in[11];
    const float* Wn4 = (const float*)d_in[12];
    const float* b4  = (const float*)d_in[13];
    float* out = (float*)d_out;

    const int N = in_sizes[0] / 64;
    const int E = in_sizes[1] / 2;

    const int nbkt = cdiv(N, BKT_NODES);                 // <=256
    int cap = E / nbkt + E / nbkt / 8 + 64;              // ~12.5% margin
    cap = (cap + 1) & ~1;                                // even (int2 align)

    // workspace layout
    unsigned* bins = (unsigned*)d_ws;                    // nbkt*cap
    int* col = (int*)(bins + (size_t)nbkt * cap);        // nbkt*cap (bucket-local)
    int2* offp = (int2*)(col + (size_t)nbkt * cap);      // N (8B-aligned: 2*nbkt*cap even)
    unsigned short* HhiA = (unsigned short*)(offp + N);  // N*64
    unsigned short* HhiB = HhiA + (size_t)N * 64;        // N*64
    unsigned short* Bth  = HhiB + (size_t)N * 64;        // 3*8192
    unsigned short* Btl  = Bth + 3 * 8192;               // 3*8192
    float* dinv = (float*)(Btl + 3 * 8192);              // N
    float* sbuf = dinv + N;                              // N
    float* gbuf = sbuf + N;                              // N
    int*   bktc = (int*)(gbuf + N);                      // 256
    int*   flag = bktc + 256;                            // 1

    const int BT = 256;
    const int gridN  = cdiv(N, BT);
    const int gridL  = cdiv(N, 16);                      // 16 nodes/block
    const int binBlocks = 512;
    const int chunksz = cdiv(E, binBlocks);

    // ---- prep: weights + init, x->bf16 ----
    bprep_init_kernel<<<96, BT, 0, stream>>>(Ws1, Wn1, Ws2, Wn2, Ws3, Wn3,
                                             Bth, Btl, ei, bktc, flag);
    split_x_kernel<<<cdiv((long long)N * 16, BT), BT, 0, stream>>>(
        (const float4*)x, (ushort4*)HhiA, N * 16);

    // ---- CSR build: 2 kernels (radix-style, write-locality-preserving) ----
    binA_kernel<<<binBlocks, BT, 0, stream>>>(ei, flag, bktc, bins, E, nbkt, cap, chunksz);
    bucketCSR_kernel<<<nbkt, BT, 0, stream>>>(bktc, bins, offp, col, dinv, N, cap);

    // ---- layers 1-3 (fused gather+dense v5, 512-thread blocks) ----
    layer_fused_kernel<<<gridL, 512, 0, stream>>>(HhiA, offp, col, dinv,
                                                  Bth, Btl, b1, HhiB, N);
    layer_fused_kernel<<<gridL, 512, 0, stream>>>(HhiB, offp, col, dinv,
                                                  Bth + 8192, Btl + 8192, b2, HhiA, N);
    layer_fused_last_kernel<<<gridL, 512, 0, stream>>>(HhiA, offp, col, dinv,
                                                       Bth + 16384, Btl + 16384, b3,
                                                       Ws4, Wn4, sbuf, gbuf, N);

    // ---- layer 4 (64->1): scalar CSR gather + sigmoid ----
    final_kernel<<<gridN, BT, 0, stream>>>(sbuf, dinv, gbuf, offp, col, b4, out, N);
}